// Round 1
// baseline (1064.808 us; speedup 1.0000x reference)
//
#include <hip/hip_runtime.h>
#include <hip/hip_bf16.h>

// Problem constants (also derived from in_sizes in kernel_launch):
//   N=50000 nodes, R=16 relations, H=64 hidden, L=32 labels, E=1.6M edges
// Kernels hard-code H=64 (lane==h) and L=32 (lane&31==l) for the wave layout.

__global__ void count_kernel(const int* __restrict__ dst, const int* __restrict__ et,
                             int* __restrict__ cnt, int E, int N) {
    int i = blockIdx.x * blockDim.x + threadIdx.x;
    int stride = gridDim.x * blockDim.x;
    for (; i < E; i += stride) {
        atomicAdd(&cnt[et[i] * N + dst[i]], 1);
    }
}

// One wave per edge, lane = h. h1[d, h] += w1[rel, s, h] / cnt[rel, d]
__global__ void layer1_kernel(const int* __restrict__ src, const int* __restrict__ dst,
                              const int* __restrict__ et, const int* __restrict__ cnt,
                              const float* __restrict__ w1, float* __restrict__ h1,
                              int E, int N) {
    int lane = threadIdx.x & 63;
    int wave = (blockIdx.x * blockDim.x + threadIdx.x) >> 6;
    int nwaves = (gridDim.x * blockDim.x) >> 6;
    for (int e = wave; e < E; e += nwaves) {
        int r = et[e];
        int s = src[e];
        int d = dst[e];
        float inv = 1.0f / (float)cnt[r * N + d];   // >=1: this edge exists
        float v = w1[((size_t)r * N + s) * 64 + lane] * inv;
        atomicAdd(&h1[(size_t)d * 64 + lane], v);
    }
}

// x = relu(h1 + root1 + bias1), in place over h1
__global__ void x_kernel(float* __restrict__ h1, const float* __restrict__ root1,
                         const float* __restrict__ bias1, int NH) {
    int i = blockIdx.x * blockDim.x + threadIdx.x;
    int stride = gridDim.x * blockDim.x;
    for (; i < NH; i += stride) {
        float v = h1[i] + root1[i] + bias1[i & 63];
        h1[i] = v > 0.0f ? v : 0.0f;
    }
}

// One wave per edge. lane -> (l = lane&31, half = lane>>5).
// acc(l, half) = sum_{h in half*32..half*32+31} x[s,h] * w2[r,h,l]
// combine halves with shfl_xor(32); lanes 0..31 atomically add acc/cnt into out[d, l].
__global__ void layer2_kernel(const int* __restrict__ src, const int* __restrict__ dst,
                              const int* __restrict__ et, const int* __restrict__ cnt,
                              const float* __restrict__ x, const float* __restrict__ w2,
                              float* __restrict__ out, int E, int N) {
    int lane = threadIdx.x & 63;
    int l = lane & 31;
    int half = lane >> 5;
    int wave = (blockIdx.x * blockDim.x + threadIdx.x) >> 6;
    int nwaves = (gridDim.x * blockDim.x) >> 6;
    for (int e = wave; e < E; e += nwaves) {
        int r = et[e];
        int s = src[e];
        int d = dst[e];
        float inv = 1.0f / (float)cnt[r * N + d];
        float xv = x[(size_t)s * 64 + lane];        // lane-th feature of src row
        const float* w2r = w2 + ((size_t)r * 64 + half * 32) * 32 + l;
        float acc = 0.0f;
#pragma unroll
        for (int i = 0; i < 32; ++i) {
            float xs = __shfl(xv, half * 32 + i, 64);
            acc += xs * w2r[(size_t)i * 32];
        }
        acc += __shfl_xor(acc, 32, 64);             // combine the two h-halves
        if (half == 0) {
            atomicAdd(&out[(size_t)d * 32 + l], acc * inv);
        }
    }
}

// out = sigmoid(out_acc + x @ root2 + bias2)
__global__ void final_kernel(float* __restrict__ out, const float* __restrict__ x,
                             const float* __restrict__ root2, const float* __restrict__ bias2,
                             int N) {
    int idx = blockIdx.x * blockDim.x + threadIdx.x;
    int stride = gridDim.x * blockDim.x;
    int total = N * 32;
    for (; idx < total; idx += stride) {
        int n = idx >> 5;
        int l = idx & 31;
        float acc = out[idx] + bias2[l];
        const float* xr = x + (size_t)n * 64;
#pragma unroll
        for (int h = 0; h < 64; ++h) {
            acc += xr[h] * root2[h * 32 + l];
        }
        out[idx] = 1.0f / (1.0f + __expf(-acc));
    }
}

extern "C" void kernel_launch(void* const* d_in, const int* in_sizes, int n_in,
                              void* d_out, int out_size, void* d_ws, size_t ws_size,
                              hipStream_t stream) {
    const int*   edge_index = (const int*)d_in[0];   // [2, E]
    const int*   edge_type  = (const int*)d_in[1];   // [E]
    const float* w1         = (const float*)d_in[2]; // [R, N, 64]
    const float* root1      = (const float*)d_in[3]; // [N, 64]
    const float* bias1      = (const float*)d_in[4]; // [64]
    const float* w2         = (const float*)d_in[5]; // [R, 64, 32]
    const float* root2      = (const float*)d_in[6]; // [64, 32]
    const float* bias2      = (const float*)d_in[7]; // [32]
    float* out = (float*)d_out;

    int E = in_sizes[1];
    int H = in_sizes[4];            // 64
    int L = in_sizes[7];            // 32
    int N = in_sizes[3] / H;
    int R = in_sizes[5] / (H * L);

    const int* src = edge_index;
    const int* dst = edge_index + E;

    // Workspace layout: [cnt: R*N ints][h1: N*H floats]  (~16 MB)
    char* ws = (char*)d_ws;
    int*   cnt = (int*)ws;
    float* h1  = (float*)(ws + (size_t)R * N * sizeof(int));

    // zero accumulators (contiguous cnt+h1 region, and the out accumulator)
    hipMemsetAsync(cnt, 0, (size_t)R * N * sizeof(int) + (size_t)N * H * sizeof(float), stream);
    hipMemsetAsync(out, 0, (size_t)N * L * sizeof(float), stream);

    count_kernel <<<2048, 256, 0, stream>>>(dst, edge_type, cnt, E, N);
    layer1_kernel<<<4096, 256, 0, stream>>>(src, dst, edge_type, cnt, w1, h1, E, N);
    x_kernel     <<<2048, 256, 0, stream>>>(h1, root1, bias1, N * H);
    layer2_kernel<<<4096, 256, 0, stream>>>(src, dst, edge_type, cnt, h1, w2, out, E, N);
    final_kernel <<<2048, 256, 0, stream>>>(out, h1, root2, bias2, N);
}

// Round 2
// 735.337 us; speedup vs baseline: 1.4481x; 1.4481x over previous
//
#include <hip/hip_runtime.h>
#include <hip/hip_bf16.h>

// N=50000 nodes, R=16 relations, H=64 hidden, L=32 labels, E=1.6M edges
// Kernels hard-code H=64 (lane==h) and L=32 (lane&31==l).

__global__ void count_kernel(const int* __restrict__ dst, const int* __restrict__ et,
                             int* __restrict__ cnt, int E, int N) {
    int i = blockIdx.x * blockDim.x + threadIdx.x;
    int stride = gridDim.x * blockDim.x;
    for (; i < E; i += stride) {
        atomicAdd(&cnt[et[i] * N + dst[i]], 1);
    }
}

// One wave per edge, lane = h. h1[d, h] += w1[rel, s, h] / cnt[rel, d]
__global__ void layer1_kernel(const int* __restrict__ src, const int* __restrict__ dst,
                              const int* __restrict__ et, const int* __restrict__ cnt,
                              const float* __restrict__ w1, float* __restrict__ h1,
                              int E, int N) {
    int lane = threadIdx.x & 63;
    int wave = (blockIdx.x * blockDim.x + threadIdx.x) >> 6;
    int nwaves = (gridDim.x * blockDim.x) >> 6;
    for (int e = wave; e < E; e += nwaves) {
        int r = et[e];
        int s = src[e];
        int d = dst[e];
        float inv = 1.0f / (float)cnt[r * N + d];
        float v = w1[((size_t)r * N + s) * 64 + lane] * inv;
        atomicAdd(&h1[(size_t)d * 64 + lane], v);
    }
}

// x = relu(h1 + root1 + bias1), in place over h1
__global__ void x_kernel(float* __restrict__ h1, const float* __restrict__ root1,
                         const float* __restrict__ bias1, int NH) {
    int i = blockIdx.x * blockDim.x + threadIdx.x;
    int stride = gridDim.x * blockDim.x;
    for (; i < NH; i += stride) {
        float v = h1[i] + root1[i] + bias1[i & 63];
        h1[i] = v > 0.0f ? v : 0.0f;
    }
}

// z[n, r*32+l] = sum_h x[n,h] * w2[r,h,l]   (z layout [N, R*L] so the edge
// gather for (s,r) reads one contiguous 128B row-chunk)
// Each thread owns two fixed (r,l) columns of w2, preloaded into registers,
// and grid-strides over nodes; x row staged in LDS (broadcast reads).
__global__ void zgemm_kernel(const float* __restrict__ x, const float* __restrict__ w2,
                             float* __restrict__ z, int N) {
    __shared__ float xs[64];
    int t = threadIdx.x;          // 256 threads
    int o0 = t, o1 = t + 256;     // output columns in [0, 512)
    // preload w2 columns (r = o>>5, l = o&31): w2[r, h, l], h = 0..63
    float wc0[64], wc1[64];
    {
        const float* w0 = w2 + (size_t)(o0 >> 5) * 64 * 32 + (o0 & 31);
        const float* w1p = w2 + (size_t)(o1 >> 5) * 64 * 32 + (o1 & 31);
#pragma unroll
        for (int h = 0; h < 64; ++h) {
            wc0[h] = w0[h * 32];
            wc1[h] = w1p[h * 32];
        }
    }
    for (int n = blockIdx.x; n < N; n += gridDim.x) {
        __syncthreads();
        if (t < 64) xs[t] = x[(size_t)n * 64 + t];
        __syncthreads();
        float a0 = 0.0f, a1 = 0.0f;
#pragma unroll
        for (int h = 0; h < 64; ++h) {
            float xv = xs[h];
            a0 += xv * wc0[h];
            a1 += xv * wc1[h];
        }
        z[(size_t)n * 512 + o0] = a0;
        z[(size_t)n * 512 + o1] = a1;
    }
}

// One wave per 2 edges; lane = sub*32 + l.
// out[d, l] += z[s, r*32+l] / cnt[r, d]
__global__ void layer2_scatter(const int* __restrict__ src, const int* __restrict__ dst,
                               const int* __restrict__ et, const int* __restrict__ cnt,
                               const float* __restrict__ z, float* __restrict__ out,
                               int E, int N, int R) {
    int lane = threadIdx.x & 63;
    int sub = lane >> 5;
    int l = lane & 31;
    int wave = (blockIdx.x * blockDim.x + threadIdx.x) >> 6;
    int nwaves = (gridDim.x * blockDim.x) >> 6;
    for (int base = wave * 2; base < E; base += nwaves * 2) {
        int e = base + sub;
        if (e < E) {
            int r = et[e];
            int s = src[e];
            int d = dst[e];
            float inv = 1.0f / (float)cnt[r * N + d];
            float v = z[((size_t)s * R + r) * 32 + l] * inv;
            atomicAdd(&out[(size_t)d * 32 + l], v);
        }
    }
}

// Fallback (small ws): per-edge matvec, one wave per edge.
__global__ void layer2_kernel(const int* __restrict__ src, const int* __restrict__ dst,
                              const int* __restrict__ et, const int* __restrict__ cnt,
                              const float* __restrict__ x, const float* __restrict__ w2,
                              float* __restrict__ out, int E, int N) {
    int lane = threadIdx.x & 63;
    int l = lane & 31;
    int half = lane >> 5;
    int wave = (blockIdx.x * blockDim.x + threadIdx.x) >> 6;
    int nwaves = (gridDim.x * blockDim.x) >> 6;
    for (int e = wave; e < E; e += nwaves) {
        int r = et[e];
        int s = src[e];
        int d = dst[e];
        float inv = 1.0f / (float)cnt[r * N + d];
        float xv = x[(size_t)s * 64 + lane];
        const float* w2r = w2 + ((size_t)r * 64 + half * 32) * 32 + l;
        float acc = 0.0f;
#pragma unroll
        for (int i = 0; i < 32; ++i) {
            float xs = __shfl(xv, half * 32 + i, 64);
            acc += xs * w2r[(size_t)i * 32];
        }
        acc += __shfl_xor(acc, 32, 64);
        if (half == 0) {
            atomicAdd(&out[(size_t)d * 32 + l], acc * inv);
        }
    }
}

// out = sigmoid(out_acc + x @ root2 + bias2)
__global__ void final_kernel(float* __restrict__ out, const float* __restrict__ x,
                             const float* __restrict__ root2, const float* __restrict__ bias2,
                             int N) {
    int idx = blockIdx.x * blockDim.x + threadIdx.x;
    int stride = gridDim.x * blockDim.x;
    int total = N * 32;
    for (; idx < total; idx += stride) {
        int n = idx >> 5;
        int l = idx & 31;
        float acc = out[idx] + bias2[l];
        const float* xr = x + (size_t)n * 64;
#pragma unroll
        for (int h = 0; h < 64; ++h) {
            acc += xr[h] * root2[h * 32 + l];
        }
        out[idx] = 1.0f / (1.0f + __expf(-acc));
    }
}

extern "C" void kernel_launch(void* const* d_in, const int* in_sizes, int n_in,
                              void* d_out, int out_size, void* d_ws, size_t ws_size,
                              hipStream_t stream) {
    const int*   edge_index = (const int*)d_in[0];   // [2, E]
    const int*   edge_type  = (const int*)d_in[1];   // [E]
    const float* w1         = (const float*)d_in[2]; // [R, N, 64]
    const float* root1      = (const float*)d_in[3]; // [N, 64]
    const float* bias1      = (const float*)d_in[4]; // [64]
    const float* w2         = (const float*)d_in[5]; // [R, 64, 32]
    const float* root2      = (const float*)d_in[6]; // [64, 32]
    const float* bias2      = (const float*)d_in[7]; // [32]
    float* out = (float*)d_out;

    int E = in_sizes[1];
    int H = in_sizes[4];            // 64
    int L = in_sizes[7];            // 32
    int N = in_sizes[3] / H;
    int R = in_sizes[5] / (H * L);

    const int* src = edge_index;
    const int* dst = edge_index + E;

    // Workspace layout: [cnt: R*N ints][h1: N*H floats][z: N*R*L floats]
    size_t cnt_bytes = (size_t)R * N * sizeof(int);
    size_t h1_bytes  = (size_t)N * H * sizeof(float);
    size_t z_bytes   = (size_t)N * R * L * sizeof(float);
    char* ws = (char*)d_ws;
    int*   cnt = (int*)ws;
    float* h1  = (float*)(ws + cnt_bytes);
    float* z   = (float*)(ws + cnt_bytes + h1_bytes);
    bool use_z = (ws_size >= cnt_bytes + h1_bytes + z_bytes);

    hipMemsetAsync(cnt, 0, cnt_bytes + h1_bytes, stream);
    hipMemsetAsync(out, 0, (size_t)N * L * sizeof(float), stream);

    count_kernel <<<2048, 256, 0, stream>>>(dst, edge_type, cnt, E, N);
    layer1_kernel<<<4096, 256, 0, stream>>>(src, dst, edge_type, cnt, w1, h1, E, N);
    x_kernel     <<<2048, 256, 0, stream>>>(h1, root1, bias1, N * H);
    if (use_z) {
        zgemm_kernel  <<<2048, 256, 0, stream>>>(h1, w2, z, N);
        layer2_scatter<<<4096, 256, 0, stream>>>(src, dst, edge_type, cnt, z, out, E, N, R);
    } else {
        layer2_kernel <<<4096, 256, 0, stream>>>(src, dst, edge_type, cnt, h1, w2, out, E, N);
    }
    final_kernel <<<2048, 256, 0, stream>>>(out, h1, root2, bias2, N);
}